// Round 5
// baseline (497.517 us; speedup 1.0000x reference)
//
#include <hip/hip_runtime.h>

#define N_NODES 100000
#define N_EDGES 1600000
#define IN_DIM 256
#define OUT_DIM 32

#define NBUCK 1564          // ceil(100000 / 64) buckets, bucket = dst >> 6
#define BNODES 64           // nodes per bucket
#define BCAP 1216           // per-bucket edge capacity (mean 1023, +6 sigma)
#define CNT_STRIDE 32       // counter padding: 1 counter per 128B line

// ---------------------------------------------------------------------------
// k_bin: single edge pass. deg_out counting + coarse bucket append.
// Payload: (dst & 63) << 17 | src   (src < 2^17)
// ---------------------------------------------------------------------------
__global__ __launch_bounds__(256) void k_bin(const int* __restrict__ src,
                                             const int* __restrict__ dst,
                                             int* __restrict__ deg_out,
                                             int* __restrict__ gcnt,
                                             unsigned* __restrict__ gbin) {
    int e = blockIdx.x * 256 + threadIdx.x;
    if (e >= N_EDGES) return;
    int s = src[e];
    int d = dst[e];
    atomicAdd(&deg_out[s], 1);
    int b = d >> 6;
    int pos = atomicAdd(&gcnt[b * CNT_STRIDE], 1);
    if (pos < BCAP)  // defensive; P(overflow) ~ 0 for random dst
        gbin[(size_t)b * BCAP + pos] = ((unsigned)(d & 63) << 17) | (unsigned)s;
}

// ---------------------------------------------------------------------------
// k_gemm: h = (x @ W) * norm_src   (unchanged from R4: W in LDS, no K-loop
// barriers, 4x4 thread tile, norm folded into epilogue)
// ---------------------------------------------------------------------------
__global__ __launch_bounds__(256) void k_gemm(const float* __restrict__ x,
                                              const float* __restrict__ W,
                                              const int* __restrict__ deg_out,
                                              float* __restrict__ h) {
    __shared__ float Wl[IN_DIM][OUT_DIM];  // 32 KB

    const int tid = threadIdx.x;

    {
        float4* Wl4 = reinterpret_cast<float4*>(&Wl[0][0]);
        const float4* W4 = reinterpret_cast<const float4*>(W);
        #pragma unroll
        for (int i = 0; i < 8; ++i)
            Wl4[tid + i * 256] = W4[tid + i * 256];
    }

    const int rg = tid >> 3;
    const int cg = tid & 7;
    const int row0 = blockIdx.x * 128 + rg * 4;
    const int co = cg * 4;

    const float4* xp[4];
    #pragma unroll
    for (int r = 0; r < 4; ++r) {
        int rr = row0 + r;
        if (rr > N_NODES - 1) rr = N_NODES - 1;
        xp[r] = reinterpret_cast<const float4*>(&x[(size_t)rr * IN_DIM]);
    }

    float acc[4][4];
    #pragma unroll
    for (int r = 0; r < 4; ++r)
        #pragma unroll
        for (int c = 0; c < 4; ++c) acc[r][c] = 0.f;

    __syncthreads();

    #pragma unroll 4
    for (int k4 = 0; k4 < IN_DIM / 4; ++k4) {
        float4 w0 = *reinterpret_cast<const float4*>(&Wl[k4 * 4 + 0][co]);
        float4 w1 = *reinterpret_cast<const float4*>(&Wl[k4 * 4 + 1][co]);
        float4 w2 = *reinterpret_cast<const float4*>(&Wl[k4 * 4 + 2][co]);
        float4 w3 = *reinterpret_cast<const float4*>(&Wl[k4 * 4 + 3][co]);
        #pragma unroll
        for (int r = 0; r < 4; ++r) {
            float4 xv = xp[r][k4];
            acc[r][0] += xv.x * w0.x + xv.y * w1.x + xv.z * w2.x + xv.w * w3.x;
            acc[r][1] += xv.x * w0.y + xv.y * w1.y + xv.z * w2.y + xv.w * w3.y;
            acc[r][2] += xv.x * w0.z + xv.y * w1.z + xv.z * w2.z + xv.w * w3.z;
            acc[r][3] += xv.x * w0.w + xv.y * w1.w + xv.z * w2.w + xv.w * w3.w;
        }
    }

    #pragma unroll
    for (int r = 0; r < 4; ++r) {
        int grow = row0 + r;
        if (grow < N_NODES) {
            int dg = deg_out[grow];
            float nrm = rsqrtf((float)(dg > 1 ? dg : 1));
            float4 v = make_float4(acc[r][0] * nrm, acc[r][1] * nrm,
                                   acc[r][2] * nrm, acc[r][3] * nrm);
            *reinterpret_cast<float4*>(&h[(size_t)grow * OUT_DIM + co]) = v;
        }
    }
}

// ---------------------------------------------------------------------------
// k_agg: one block per bucket. LDS f32 accumulators for 64 nodes x 32 cols.
// deg_in counted locally. 8-deep load pipeline on the h gathers.
// ---------------------------------------------------------------------------
__global__ __launch_bounds__(256) void k_agg(const int* __restrict__ gcnt,
                                             const unsigned* __restrict__ gbin,
                                             const float* __restrict__ h,
                                             const float* __restrict__ bias,
                                             float* __restrict__ out) {
    __shared__ float acc[BNODES][OUT_DIM];   // 8 KB, bank = col -> conflict-free
    __shared__ int ncnt[BNODES];
    __shared__ float nrml[BNODES];
    __shared__ unsigned pstage[BCAP];        // 4864 B

    const int b = blockIdx.x;
    const int tid = threadIdx.x;

    float* az = &acc[0][0];
    #pragma unroll
    for (int i = 0; i < (BNODES * OUT_DIM) / 256; ++i) az[tid + i * 256] = 0.f;
    if (tid < BNODES) ncnt[tid] = 0;

    int cnt = gcnt[b * CNT_STRIDE];
    if (cnt > BCAP) cnt = BCAP;
    const unsigned* bp = gbin + (size_t)b * BCAP;
    const int c = tid & 31;
    const int j0 = tid >> 5;
    __syncthreads();

    // stage payloads (coalesced)
    for (int i = tid; i < cnt; i += 256) pstage[i] = bp[i];
    __syncthreads();

    for (int base = 0; base < cnt; base += 64) {
        float hv[8];
        int nd[8];
        bool ok[8];
        #pragma unroll
        for (int i = 0; i < 8; ++i) {
            int j = base + j0 + i * 8;
            ok[i] = (j < cnt);
            unsigned pay = ok[i] ? pstage[j] : 0u;
            nd[i] = (int)(pay >> 17);
            int s = (int)(pay & 0x1FFFF);
            hv[i] = ok[i] ? h[(size_t)s * OUT_DIM + c] : 0.f;  // 8 indep loads
        }
        #pragma unroll
        for (int i = 0; i < 8; ++i) {
            if (ok[i]) {
                atomicAdd(&acc[nd[i]][c], hv[i]);       // ds_add_f32
                if (c == 0) atomicAdd(&ncnt[nd[i]], 1); // deg_in, local
            }
        }
    }
    __syncthreads();

    if (tid < BNODES) {
        int dg = ncnt[tid];
        nrml[tid] = rsqrtf((float)(dg > 1 ? dg : 1));
    }
    __syncthreads();

    const int n0 = b * BNODES;
    #pragma unroll
    for (int it = 0; it < (BNODES * OUT_DIM) / 256; ++it) {
        int idx = tid + it * 256;
        int row = idx >> 5;
        int col = idx & 31;
        int g = n0 + row;
        if (g < N_NODES)
            out[(size_t)g * OUT_DIM + col] = acc[row][col] * nrml[row] + bias[col];
    }
}

// ---------------------------------------------------------------------------
extern "C" void kernel_launch(void* const* d_in, const int* in_sizes, int n_in,
                              void* d_out, int out_size, void* d_ws, size_t ws_size,
                              hipStream_t stream) {
    const float* x   = (const float*)d_in[0];
    const int*   src = (const int*)d_in[1];
    const int*   dst = (const int*)d_in[2];
    const float* W   = (const float*)d_in[3];
    const float* b   = (const float*)d_in[4];
    float* out = (float*)d_out;

    // ws layout: deg_out int[N] | h float[N*32] | gcnt int[NBUCK*32] | gbin u32[NBUCK*BCAP]
    int* deg_out   = (int*)d_ws;
    float* h       = (float*)(deg_out + N_NODES);
    int* gcnt      = (int*)(h + (size_t)N_NODES * OUT_DIM);
    unsigned* gbin = (unsigned*)(gcnt + NBUCK * CNT_STRIDE);

    hipMemsetAsync(deg_out, 0, N_NODES * sizeof(int), stream);
    hipMemsetAsync(gcnt, 0, NBUCK * CNT_STRIDE * sizeof(int), stream);

    k_bin<<<(N_EDGES + 255) / 256, 256, 0, stream>>>(src, dst, deg_out, gcnt, gbin);

    k_gemm<<<(N_NODES + 127) / 128, 256, 0, stream>>>(x, W, deg_out, h);

    k_agg<<<NBUCK, 256, 0, stream>>>(gcnt, gbin, h, b, out);
}

// Round 6
// 202.355 us; speedup vs baseline: 2.4586x; 2.4586x over previous
//
#include <hip/hip_runtime.h>

#define N_NODES 100000
#define N_EDGES 1600000
#define IN_DIM 256
#define OUT_DIM 32

#define SB_SHIFT 8                          // super-bucket = dst >> 8 (256 nodes)
#define NSB ((N_NODES + 255) >> 8)          // 391
#define SBCAP 4480                          // mean 4092 + ~6 sigma
#define EBLK 8192                           // edges per part1 block
#define NB1 ((N_EDGES + EBLK - 1) / EBLK)   // 196

// ---------------------------------------------------------------------------
// k_part1: block-local histogram over 391 super-buckets, ONE global claim per
// (block,bucket), then scatter payloads into the block's private window of
// each bucket tail. Also counts deg_out. Kills cross-XCD false sharing.
// ---------------------------------------------------------------------------
__global__ __launch_bounds__(512) void k_part1(const int* __restrict__ src,
                                               const int* __restrict__ dst,
                                               int* __restrict__ deg_out,
                                               int* __restrict__ gcnt,
                                               unsigned* __restrict__ gsb) {
    __shared__ int hist[NSB];
    __shared__ int bbase[NSB];
    __shared__ int cur[NSB];
    const int tid = threadIdx.x;
    const int e0 = blockIdx.x * EBLK;
    const int eend = min(e0 + EBLK, N_EDGES);

    for (int i = tid; i < NSB; i += 512) { hist[i] = 0; cur[i] = 0; }
    __syncthreads();

    // pass A: local histogram + deg_out counting
    for (int e = e0 + tid; e < eend; e += 512) {
        atomicAdd(&hist[dst[e] >> SB_SHIFT], 1);
        atomicAdd(&deg_out[src[e]], 1);
    }
    __syncthreads();

    // claim a contiguous window per bucket (76K atomics total, not 1.6M)
    for (int i = tid; i < NSB; i += 512)
        bbase[i] = atomicAdd(&gcnt[i], hist[i]);
    __syncthreads();

    // pass B: re-read (L2-hot) and scatter into private windows
    for (int e = e0 + tid; e < eend; e += 512) {
        int d = dst[e];
        int s = src[e];
        int r = d >> SB_SHIFT;
        int lp = atomicAdd(&cur[r], 1);
        int pos = bbase[r] + lp;
        if (pos < SBCAP)   // defensive; P(overflow) ~ 1e-7
            gsb[(size_t)r * SBCAP + pos] = ((unsigned)(d & 255) << 17) | (unsigned)s;
    }
}

// ---------------------------------------------------------------------------
// k_scanb: exclusive scan of gcnt[391] -> sbase (single block)
// ---------------------------------------------------------------------------
__global__ __launch_bounds__(512) void k_scanb(const int* __restrict__ gcnt,
                                               int* __restrict__ sbase) {
    __shared__ int s[512];
    int tid = threadIdx.x;
    int v = (tid < NSB) ? min(gcnt[tid], SBCAP) : 0;
    s[tid] = v;
    __syncthreads();
    #pragma unroll
    for (int off = 1; off < 512; off <<= 1) {
        int t = (tid >= off) ? s[tid - off] : 0;
        __syncthreads();
        s[tid] += t;
        __syncthreads();
    }
    if (tid < NSB) sbase[tid] = s[tid] - v;
}

// ---------------------------------------------------------------------------
// k_gemm: h = (x @ W) * norm_src  (unchanged from R4 — left top-5 there)
// ---------------------------------------------------------------------------
__global__ __launch_bounds__(256) void k_gemm(const float* __restrict__ x,
                                              const float* __restrict__ W,
                                              const int* __restrict__ deg_out,
                                              float* __restrict__ h) {
    __shared__ float Wl[IN_DIM][OUT_DIM];  // 32 KB

    const int tid = threadIdx.x;
    {
        float4* Wl4 = reinterpret_cast<float4*>(&Wl[0][0]);
        const float4* W4 = reinterpret_cast<const float4*>(W);
        #pragma unroll
        for (int i = 0; i < 8; ++i)
            Wl4[tid + i * 256] = W4[tid + i * 256];
    }

    const int rg = tid >> 3;
    const int cg = tid & 7;
    const int row0 = blockIdx.x * 128 + rg * 4;
    const int co = cg * 4;

    const float4* xp[4];
    #pragma unroll
    for (int r = 0; r < 4; ++r) {
        int rr = row0 + r;
        if (rr > N_NODES - 1) rr = N_NODES - 1;
        xp[r] = reinterpret_cast<const float4*>(&x[(size_t)rr * IN_DIM]);
    }

    float acc[4][4];
    #pragma unroll
    for (int r = 0; r < 4; ++r)
        #pragma unroll
        for (int c = 0; c < 4; ++c) acc[r][c] = 0.f;

    __syncthreads();

    #pragma unroll 4
    for (int k4 = 0; k4 < IN_DIM / 4; ++k4) {
        float4 w0 = *reinterpret_cast<const float4*>(&Wl[k4 * 4 + 0][co]);
        float4 w1 = *reinterpret_cast<const float4*>(&Wl[k4 * 4 + 1][co]);
        float4 w2 = *reinterpret_cast<const float4*>(&Wl[k4 * 4 + 2][co]);
        float4 w3 = *reinterpret_cast<const float4*>(&Wl[k4 * 4 + 3][co]);
        #pragma unroll
        for (int r = 0; r < 4; ++r) {
            float4 xv = xp[r][k4];
            acc[r][0] += xv.x * w0.x + xv.y * w1.x + xv.z * w2.x + xv.w * w3.x;
            acc[r][1] += xv.x * w0.y + xv.y * w1.y + xv.z * w2.y + xv.w * w3.y;
            acc[r][2] += xv.x * w0.z + xv.y * w1.z + xv.z * w2.z + xv.w * w3.z;
            acc[r][3] += xv.x * w0.w + xv.y * w1.w + xv.z * w2.w + xv.w * w3.w;
        }
    }

    #pragma unroll
    for (int r = 0; r < 4; ++r) {
        int grow = row0 + r;
        if (grow < N_NODES) {
            int dg = deg_out[grow];
            float nrm = rsqrtf((float)(dg > 1 ? dg : 1));
            float4 v = make_float4(acc[r][0] * nrm, acc[r][1] * nrm,
                                   acc[r][2] * nrm, acc[r][3] * nrm);
            *reinterpret_cast<float4*>(&h[(size_t)grow * OUT_DIM + co]) = v;
        }
    }
}

// ---------------------------------------------------------------------------
// k_part2: one block per super-bucket. Exact counting sort of <=SBCAP edges
// over 256 nodes. esrc segment is block-private -> scattered writes coalesce
// in this XCD's L2. Emits row_ptr and deg_in coalesced.
// ---------------------------------------------------------------------------
__global__ __launch_bounds__(256) void k_part2(const int* __restrict__ gcnt,
                                               const int* __restrict__ sbase,
                                               const unsigned* __restrict__ gsb,
                                               int* __restrict__ row_ptr,
                                               int* __restrict__ deg_in,
                                               int* __restrict__ esrc) {
    __shared__ int hist[256];
    __shared__ int pref[256];
    __shared__ int cur[256];
    const int r = blockIdx.x;
    const int tid = threadIdx.x;
    int cnt = gcnt[r];
    if (cnt > SBCAP) cnt = SBCAP;
    const unsigned* bp = gsb + (size_t)r * SBCAP;
    const int base = sbase[r];

    hist[tid] = 0;
    cur[tid] = 0;
    __syncthreads();

    for (int i = tid; i < cnt; i += 256)
        atomicAdd(&hist[bp[i] >> 17], 1);
    __syncthreads();

    // exclusive scan of hist
    int v = hist[tid];
    pref[tid] = v;
    __syncthreads();
    #pragma unroll
    for (int off = 1; off < 256; off <<= 1) {
        int t = (tid >= off) ? pref[tid - off] : 0;
        __syncthreads();
        pref[tid] += t;
        __syncthreads();
    }
    int excl = pref[tid] - v;

    int n = (r << SB_SHIFT) + tid;
    if (n < N_NODES) {
        row_ptr[n] = base + excl;
        deg_in[n] = v;
    }
    __syncthreads();
    pref[tid] = excl;
    __syncthreads();

    for (int i = tid; i < cnt; i += 256) {
        unsigned pay = bp[i];
        int l = (int)(pay >> 17);
        int lp = atomicAdd(&cur[l], 1);
        esrc[base + pref[l] + lp] = (int)(pay & 0x1FFFF);
    }
}

// ---------------------------------------------------------------------------
// k_gather v2: wave per node, 8 edges/round (lane = edge<3b> x colquad<3b>,
// float4 per lane) -> 8 lines in flight per wave; shfl_xor reduce; fused
// norm_dst + bias.
// ---------------------------------------------------------------------------
__global__ __launch_bounds__(256) void k_gather(const int* __restrict__ esrc,
                                                const int* __restrict__ row_ptr,
                                                const int* __restrict__ deg_in,
                                                const float* __restrict__ h,
                                                const float* __restrict__ bias,
                                                float* __restrict__ out) {
    int node = (blockIdx.x * 256 + threadIdx.x) >> 6;
    if (node >= N_NODES) return;
    int lane = threadIdx.x & 63;
    int j0 = lane >> 3;   // edge slot 0..7
    int q  = lane & 7;    // col quad 0..7

    int start = row_ptr[node];
    int deg = deg_in[node];

    float4 acc = make_float4(0.f, 0.f, 0.f, 0.f);
    int rounds = (deg + 7) >> 3;
    for (int rr = 0; rr < rounds; ++rr) {
        int j = rr * 8 + j0;
        if (j < deg) {
            int s = esrc[start + j];
            float4 hv = *reinterpret_cast<const float4*>(&h[(size_t)s * OUT_DIM + q * 4]);
            acc.x += hv.x; acc.y += hv.y; acc.z += hv.z; acc.w += hv.w;
        }
    }
    #pragma unroll
    for (int m = 8; m <= 32; m <<= 1) {
        acc.x += __shfl_xor(acc.x, m);
        acc.y += __shfl_xor(acc.y, m);
        acc.z += __shfl_xor(acc.z, m);
        acc.w += __shfl_xor(acc.w, m);
    }
    if (j0 == 0) {
        float nrm = rsqrtf((float)(deg > 1 ? deg : 1));
        float4 bb = *reinterpret_cast<const float4*>(&bias[q * 4]);
        float4 o = make_float4(acc.x * nrm + bb.x, acc.y * nrm + bb.y,
                               acc.z * nrm + bb.z, acc.w * nrm + bb.w);
        *reinterpret_cast<float4*>(&out[(size_t)node * OUT_DIM + q * 4]) = o;
    }
}

// ---------------------------------------------------------------------------
extern "C" void kernel_launch(void* const* d_in, const int* in_sizes, int n_in,
                              void* d_out, int out_size, void* d_ws, size_t ws_size,
                              hipStream_t stream) {
    const float* x   = (const float*)d_in[0];
    const int*   src = (const int*)d_in[1];
    const int*   dst = (const int*)d_in[2];
    const float* W   = (const float*)d_in[3];
    const float* b   = (const float*)d_in[4];
    float* out = (float*)d_out;

    // ws: deg_out[N] row_ptr[N] deg_in[N] gcnt[NSB] sbase[NSB] pad |
    //     h f32[N*32] | gsb u32[NSB*SBCAP] | esrc i32[E]
    int* deg_out = (int*)d_ws;
    int* row_ptr = deg_out + N_NODES;
    int* deg_in  = row_ptr + N_NODES;
    int* gcnt    = deg_in + N_NODES;
    int* sbase   = gcnt + NSB;
    int* pad     = sbase + NSB;                  // 300782 ints
    float* h     = (float*)(pad + 2);            // 300784 ints -> 16B aligned
    unsigned* gsb = (unsigned*)(h + (size_t)N_NODES * OUT_DIM);
    int* esrc    = (int*)(gsb + (size_t)NSB * SBCAP);

    hipMemsetAsync(deg_out, 0, N_NODES * sizeof(int), stream);
    hipMemsetAsync(gcnt, 0, NSB * sizeof(int), stream);

    k_part1<<<NB1, 512, 0, stream>>>(src, dst, deg_out, gcnt, gsb);

    k_scanb<<<1, 512, 0, stream>>>(gcnt, sbase);

    k_gemm<<<(N_NODES + 127) / 128, 256, 0, stream>>>(x, W, deg_out, h);

    k_part2<<<NSB, 256, 0, stream>>>(gcnt, sbase, gsb, row_ptr, deg_in, esrc);

    k_gather<<<(N_NODES * 64 + 255) / 256, 256, 0, stream>>>(esrc, row_ptr, deg_in, h, b, out);
}